// Round 9
// baseline (2921.802 us; speedup 1.0000x reference)
//
#include <hip/hip_runtime.h>
#include <hip/hip_bf16.h>
#include <stdint.h>
#include <stddef.h>

typedef __hip_bfloat16 bf16;
typedef __attribute__((ext_vector_type(8))) short bfrag;
typedef __attribute__((ext_vector_type(4))) float ffrag;

#define HDIM 1024
#define BATCH 64
#define TSTEPS 256
#define GDIM 4096
#define VOCAB 32000

// xg (layer1): ((q*128 + cg)*16384 + b*256 + t)*8 + jj
// h-history: 257 slots x 128 KB; slot (256-t) = h INPUT to step t (write-once).
//   within slot (u64): half*8192 + kg*64 + b ; u64(half,cg,b) = cols cg*8+half*4+0..3
#define HSLOT 16384ull
// xpart ring: [slot8][q4][bg2][cg128][b32][jj8] f32 (8 MB)

__device__ __forceinline__ bf16 f2b(float x) { return __float2bfloat16(x); }
__device__ __forceinline__ short f2bs(float x) {
  bf16 b = __float2bfloat16(x);
  return *reinterpret_cast<short*>(&b);
}
__device__ __forceinline__ float bs2f(unsigned short u) {
  union { unsigned int i; float f; } v;
  v.i = ((unsigned int)u) << 16;
  return v.f;
}
__device__ __forceinline__ ffrag mfma16(bfrag a, bfrag b, ffrag c) {
  return __builtin_amdgcn_mfma_f32_16x16x32_bf16(a, b, c, 0, 0, 0);
}
__device__ __forceinline__ float sigm(float x) { return 1.0f / (1.0f + __expf(-x)); }
__device__ __forceinline__ float tanhfast(float x) {
  float e = __expf(2.0f * x);
  return 1.0f - 2.0f / (e + 1.0f);
}

__device__ __forceinline__ void store_u16_agent(unsigned short* p, unsigned short v) {
  __hip_atomic_store(p, v, __ATOMIC_RELAXED, __HIP_MEMORY_SCOPE_AGENT);
}
__device__ __forceinline__ unsigned long long load_u64_agent(const unsigned long long* p) {
  return __hip_atomic_load(p, __ATOMIC_RELAXED, __HIP_MEMORY_SCOPE_AGENT);
}
__device__ __forceinline__ void store_u32_agent(unsigned* p, unsigned v) {
  __hip_atomic_store(p, v, __ATOMIC_RELAXED, __HIP_MEMORY_SCOPE_AGENT);
}
__device__ __forceinline__ void store_f32_agent(float* p, float v) {
  __hip_atomic_store(p, v, __ATOMIC_RELAXED, __HIP_MEMORY_SCOPE_AGENT);
}
__device__ __forceinline__ float load_f32_agent(const float* p) {
  return __hip_atomic_load(p, __ATOMIC_RELAXED, __HIP_MEMORY_SCOPE_AGENT);
}

// ---------------- convert f32 -> bf16 ----------------
__global__ void convert_bf16_kernel(const float* __restrict__ src, bf16* __restrict__ dst, int n4) {
  int i = blockIdx.x * 256 + threadIdx.x;
  if (i >= n4) return;
  float4 v = reinterpret_cast<const float4*>(src)[i];
  ushort4 o;
  o.x = (unsigned short)f2bs(v.x);
  o.y = (unsigned short)f2bs(v.y);
  o.z = (unsigned short)f2bs(v.z);
  o.w = (unsigned short)f2bs(v.w);
  reinterpret_cast<ushort4*>(dst)[i] = o;
}

// ---------------- embedding gather -> bf16 ----------------
__global__ void embed_kernel(const int* __restrict__ ids, const float* __restrict__ table,
                             bf16* __restrict__ x, int n4) {
  int i = blockIdx.x * 256 + threadIdx.x;
  if (i >= n4) return;
  int row = i >> 8;
  int c4 = i & 255;
  int tok = ids[row];
  float4 v = reinterpret_cast<const float4*>(table)[(size_t)tok * 256 + c4];
  ushort4 o;
  o.x = (unsigned short)f2bs(v.x);
  o.y = (unsigned short)f2bs(v.y);
  o.z = (unsigned short)f2bs(v.z);
  o.w = (unsigned short)f2bs(v.w);
  reinterpret_cast<ushort4*>(x)[i] = o;
}

// ---------------- xg1 = x @ W_ih1^T + b_ih1 + b_hh1 ----------------
#define BMX 128
#define BNX 128
#define BKX 64

__launch_bounds__(256, 2)
__global__ void gemm_xg_kernel(const bf16* __restrict__ A,
                               const bf16* __restrict__ W,
                               const float* __restrict__ bih,
                               const float* __restrict__ bhh,
                               bf16* __restrict__ xg) {
  __shared__ bf16 As[BMX][BKX + 8];
  __shared__ bf16 Bs[BNX][BKX + 8];
  const int n0 = blockIdx.x * BNX;
  const int m0 = blockIdx.y * BMX;
  const int tid = threadIdx.x;
  const int w = tid >> 6, l = tid & 63;
  const int wm = (w >> 1) * 64, wn = (w & 1) * 64;
  const int lr = l & 15, lk = (l >> 4) * 8;

  ffrag acc[4][4];
#pragma unroll
  for (int i = 0; i < 4; ++i)
#pragma unroll
    for (int j = 0; j < 4; ++j) acc[i][j] = ffrag{0.f, 0.f, 0.f, 0.f};

  const int sr = tid >> 1, sh = (tid & 1) * 32;
  for (int kb = 0; kb < HDIM; kb += BKX) {
    __syncthreads();
    {
      const uint4* ga = reinterpret_cast<const uint4*>(&A[(size_t)(m0 + sr) * HDIM + kb + sh]);
      uint4* la = reinterpret_cast<uint4*>(&As[sr][sh]);
      la[0] = ga[0]; la[1] = ga[1]; la[2] = ga[2]; la[3] = ga[3];
      const uint4* gb = reinterpret_cast<const uint4*>(&W[(size_t)(n0 + sr) * HDIM + kb + sh]);
      uint4* lb = reinterpret_cast<uint4*>(&Bs[sr][sh]);
      lb[0] = gb[0]; lb[1] = gb[1]; lb[2] = gb[2]; lb[3] = gb[3];
    }
    __syncthreads();
#pragma unroll
    for (int ks = 0; ks < 2; ++ks) {
      const int ko = ks * 32 + lk;
      bfrag af[4], bfv[4];
#pragma unroll
      for (int i = 0; i < 4; ++i)
        af[i] = *reinterpret_cast<const bfrag*>(&As[wm + i * 16 + lr][ko]);
#pragma unroll
      for (int j = 0; j < 4; ++j)
        bfv[j] = *reinterpret_cast<const bfrag*>(&Bs[wn + j * 16 + lr][ko]);
#pragma unroll
      for (int i = 0; i < 4; ++i)
#pragma unroll
        for (int j = 0; j < 4; ++j)
          acc[i][j] = mfma16(af[i], bfv[j], acc[i][j]);
    }
  }
  const int rg = (l >> 4) * 4;
#pragma unroll
  for (int j = 0; j < 4; ++j) {
    const int n = n0 + wn + j * 16 + lr;
    const float bias = bih[n] + bhh[n];
    const int q = n >> 10, g = (n & 1023) >> 3, jj = n & 7;
    bf16* base = xg + (size_t)(q * 128 + g) * 16384 * 8 + jj;
#pragma unroll
    for (int i = 0; i < 4; ++i) {
#pragma unroll
      for (int r = 0; r < 4; ++r) {
        const int m = m0 + wm + i * 16 + rg + r;   // m = b*256 + t
        base[(size_t)m * 8] = f2b(acc[i][j][r] + bias);
      }
    }
  }
}

// ---------------- fused 2-layer pipelined LSTM ----------------
// 768 blocks x 128 thr (2 waves). id<256: L1 lstm; <512: L2x (y1@Wih2); else L2h lstm.
// Each block: (bg = sub&1 -> 32 batches, cg = sub>>1 -> 8 hidden cols = 32 gate cols).
// Wave w = K-half. Skewed pipeline: L2x trails L1 by 1 step, L2h by 2.
__launch_bounds__(128, 2)
__global__ void fused_lstm_kernel(const bf16* __restrict__ xg,
                                  const bf16* __restrict__ whh1,
                                  const bf16* __restrict__ whh2,
                                  const bf16* __restrict__ wih2,
                                  const float* __restrict__ bih2,
                                  const float* __restrict__ bhh2,
                                  bf16* histA, bf16* histB,
                                  float* xpart,
                                  float* __restrict__ out_h1, float* __restrict__ out_c1,
                                  float* __restrict__ out_h2, float* __restrict__ out_c2,
                                  float* __restrict__ out_last,
                                  unsigned* __restrict__ fL1,
                                  unsigned* __restrict__ fL2,
                                  unsigned* __restrict__ fx) {
  __shared__ float gxp[2][32][33];
  const int id = blockIdx.x;
  const int tid = threadIdx.x;
  const int w = tid >> 6, l = tid & 63;
  const int lr = l & 15, lkg = l >> 4;
  const int kh = w, kbase = kh * 512;
  const int eb = tid & 31, jj2 = tid >> 5;   // elementwise: batch-local, col pair id

  if (id < 256) {
    // =============== Layer-1 recurrence ===============
    const int bg = id & 1, cg = id >> 1;
    const int b_glob = bg * 32 + eb;
    bfrag breg0[16], breg1[16];
    {
      const int q = lr >> 2, ja = lr & 3;
      const size_t g0 = ((size_t)q * HDIM + cg * 8 + ja) * HDIM + kbase + lkg * 8;
      const size_t g1 = ((size_t)q * HDIM + cg * 8 + 4 + ja) * HDIM + kbase + lkg * 8;
#pragma unroll
      for (int ks = 0; ks < 16; ++ks) {
        breg0[ks] = *reinterpret_cast<const bfrag*>(&whh1[g0 + ks * 32]);
        breg1[ks] = *reinterpret_cast<const bfrag*>(&whh1[g1 + ks * 32]);
      }
    }
    float cA = 0.f, cB = 0.f;
    unsigned long long* hb = (unsigned long long*)histA;
    const size_t hb0 = (size_t)(kh * 64 + lkg) * 64 + bg * 32 + lr;
    const size_t hb1 = hb0 + 16;
    const unsigned long long* fv = (const unsigned long long*)fL1 + (size_t)bg * 128;
    const unsigned short* xgu = (const unsigned short*)xg;
    unsigned short xnA[4], xnB[4];
#pragma unroll
    for (int qq = 0; qq < 4; ++qq) {
      const size_t base = (((size_t)qq * 128 + cg) * 16384 + (size_t)b_glob * 256) * 8;
      xnA[qq] = xgu[base + jj2];
      xnB[qq] = xgu[base + 4 + jj2];
    }

#pragma unroll 1
    for (int t = 0; t < TSTEPS; ++t) {
      if (t > 0) {
        const unsigned tt = (unsigned)t;
        for (;;) {
          unsigned long long fa = load_u64_agent(&fv[l]);
          unsigned long long fb = load_u64_agent(&fv[64 + l]);
          int ok = ((unsigned)fa >= tt) && ((unsigned)(fa >> 32) >= tt) &&
                   ((unsigned)fb >= tt) && ((unsigned)(fb >> 32) >= tt);
          if (__all(ok)) break;
          __builtin_amdgcn_s_sleep(1);
        }
      }
      __builtin_amdgcn_sched_barrier(0);
      asm volatile("" ::: "memory");

      const unsigned long long* hin = hb + (size_t)(TSTEPS - t) * HSLOT;
      ffrag a00 = ffrag{0.f,0.f,0.f,0.f}, a01 = ffrag{0.f,0.f,0.f,0.f};
      ffrag a10 = ffrag{0.f,0.f,0.f,0.f}, a11 = ffrag{0.f,0.f,0.f,0.f};
#pragma unroll
      for (int ks = 0; ks < 16; ++ks) {
        union { unsigned long long u[2]; bfrag f; } r0, r1;
        r0.u[0] = hin[hb0 + ks * 256];
        r0.u[1] = hin[8192 + hb0 + ks * 256];
        r1.u[0] = hin[hb1 + ks * 256];
        r1.u[1] = hin[8192 + hb1 + ks * 256];
        a00 = mfma16(r0.f, breg0[ks], a00);
        a01 = mfma16(r0.f, breg1[ks], a01);
        a10 = mfma16(r1.f, breg0[ks], a10);
        a11 = mfma16(r1.f, breg1[ks], a11);
      }
#pragma unroll
      for (int r = 0; r < 4; ++r) {
        gxp[kh][lkg * 4 + r][lr]           = a00[r];
        gxp[kh][lkg * 4 + r][16 + lr]      = a01[r];
        gxp[kh][16 + lkg * 4 + r][lr]      = a10[r];
        gxp[kh][16 + lkg * 4 + r][16 + lr] = a11[r];
      }
      __syncthreads();

      const float giA = gxp[0][eb][jj2]      + gxp[1][eb][jj2]      + bs2f(xnA[0]);
      const float gfA = gxp[0][eb][4 + jj2]  + gxp[1][eb][4 + jj2]  + bs2f(xnA[1]);
      const float ggA = gxp[0][eb][8 + jj2]  + gxp[1][eb][8 + jj2]  + bs2f(xnA[2]);
      const float goA = gxp[0][eb][12 + jj2] + gxp[1][eb][12 + jj2] + bs2f(xnA[3]);
      const float giB = gxp[0][eb][16 + jj2]      + gxp[1][eb][16 + jj2]      + bs2f(xnB[0]);
      const float gfB = gxp[0][eb][16 + 4 + jj2]  + gxp[1][eb][16 + 4 + jj2]  + bs2f(xnB[1]);
      const float ggB = gxp[0][eb][16 + 8 + jj2]  + gxp[1][eb][16 + 8 + jj2]  + bs2f(xnB[2]);
      const float goB = gxp[0][eb][16 + 12 + jj2] + gxp[1][eb][16 + 12 + jj2] + bs2f(xnB[3]);
      cA = sigm(gfA) * cA + sigm(giA) * tanhfast(ggA);
      const float hA = sigm(goA) * tanhfast(cA);
      cB = sigm(gfB) * cB + sigm(giB) * tanhfast(ggB);
      const float hB = sigm(goB) * tanhfast(cB);

      unsigned long long* hout = hb + (size_t)(255 - t) * HSLOT;
      store_u16_agent((unsigned short*)(hout + (size_t)cg * 64 + b_glob) + jj2,
                      (unsigned short)f2bs(hA));
      store_u16_agent((unsigned short*)(hout + 8192 + (size_t)cg * 64 + b_glob) + jj2,
                      (unsigned short)f2bs(hB));
      if (t == TSTEPS - 1) {
        const int jA = cg * 8 + jj2;
        out_h1[(size_t)b_glob * HDIM + jA] = hA;
        out_h1[(size_t)b_glob * HDIM + jA + 4] = hB;
        out_c1[(size_t)b_glob * HDIM + jA] = cA;
        out_c1[(size_t)b_glob * HDIM + jA + 4] = cB;
      }
      __builtin_amdgcn_s_waitcnt(0);
      if (l == 0) store_u32_agent(&fL1[bg * 256 + cg * 2 + w], (unsigned)(t + 1));
      if (t < TSTEPS - 1) {
#pragma unroll
        for (int qq = 0; qq < 4; ++qq) {
          const size_t base =
              (((size_t)qq * 128 + cg) * 16384 + (size_t)b_glob * 256 + t + 1) * 8;
          xnA[qq] = xgu[base + jj2];
          xnB[qq] = xgu[base + 4 + jj2];
        }
      }
      __syncthreads();
      __builtin_amdgcn_sched_barrier(0);
    }
  } else if (id < 512) {
    // =============== Layer-2 x-projection: y1(t) @ Wih2^T ===============
    const int sid = id - 256;
    const int bg = sid & 1, cg = sid >> 1;
    bfrag breg0[16], breg1[16];
    {
      const int q = lr >> 2, ja = lr & 3;
      const size_t g0 = ((size_t)q * HDIM + cg * 8 + ja) * HDIM + kbase + lkg * 8;
      const size_t g1 = ((size_t)q * HDIM + cg * 8 + 4 + ja) * HDIM + kbase + lkg * 8;
#pragma unroll
      for (int ks = 0; ks < 16; ++ks) {
        breg0[ks] = *reinterpret_cast<const bfrag*>(&wih2[g0 + ks * 32]);
        breg1[ks] = *reinterpret_cast<const bfrag*>(&wih2[g1 + ks * 32]);
      }
    }
    const unsigned long long* hbA = (const unsigned long long*)histA;
    const size_t hb0 = (size_t)(kh * 64 + lkg) * 64 + bg * 32 + lr;
    const size_t hb1 = hb0 + 16;
    const unsigned long long* fv = (const unsigned long long*)fL1 + (size_t)bg * 128;
    const unsigned long long* fbp = (const unsigned long long*)fL2 + (size_t)bg * 128 + cg;

#pragma unroll 1
    for (int t = 0; t < TSTEPS; ++t) {
      {
        const unsigned tt = (unsigned)(t + 1);
        for (;;) {
          unsigned long long fa = load_u64_agent(&fv[l]);
          unsigned long long fb = load_u64_agent(&fv[64 + l]);
          int ok = ((unsigned)fa >= tt) && ((unsigned)(fa >> 32) >= tt) &&
                   ((unsigned)fb >= tt) && ((unsigned)(fb >> 32) >= tt);
          if (__all(ok)) break;
          __builtin_amdgcn_s_sleep(1);
        }
      }
      if (t >= 8) {     // ring backpressure: L2h must have consumed slot t-8
        const unsigned bp = (unsigned)(t - 7);
        for (;;) {
          unsigned long long v = load_u64_agent(fbp);
          if ((unsigned)v >= bp && (unsigned)(v >> 32) >= bp) break;
          __builtin_amdgcn_s_sleep(1);
        }
      }
      __builtin_amdgcn_sched_barrier(0);
      asm volatile("" ::: "memory");

      const unsigned long long* yin = hbA + (size_t)(255 - t) * HSLOT;
      ffrag a00 = ffrag{0.f,0.f,0.f,0.f}, a01 = ffrag{0.f,0.f,0.f,0.f};
      ffrag a10 = ffrag{0.f,0.f,0.f,0.f}, a11 = ffrag{0.f,0.f,0.f,0.f};
#pragma unroll
      for (int ks = 0; ks < 16; ++ks) {
        union { unsigned long long u[2]; bfrag f; } r0, r1;
        r0.u[0] = yin[hb0 + ks * 256];
        r0.u[1] = yin[8192 + hb0 + ks * 256];
        r1.u[0] = yin[hb1 + ks * 256];
        r1.u[1] = yin[8192 + hb1 + ks * 256];
        a00 = mfma16(r0.f, breg0[ks], a00);
        a01 = mfma16(r0.f, breg1[ks], a01);
        a10 = mfma16(r1.f, breg0[ks], a10);
        a11 = mfma16(r1.f, breg1[ks], a11);
      }
#pragma unroll
      for (int r = 0; r < 4; ++r) {
        gxp[kh][lkg * 4 + r][lr]           = a00[r];
        gxp[kh][lkg * 4 + r][16 + lr]      = a01[r];
        gxp[kh][16 + lkg * 4 + r][lr]      = a10[r];
        gxp[kh][16 + lkg * 4 + r][16 + lr] = a11[r];
      }
      __syncthreads();
#pragma unroll
      for (int q = 0; q < 4; ++q) {
        const float vA = gxp[0][eb][q * 4 + jj2]      + gxp[1][eb][q * 4 + jj2];
        const float vB = gxp[0][eb][16 + q * 4 + jj2] + gxp[1][eb][16 + q * 4 + jj2];
        const size_t ib =
            ((((size_t)(t & 7) * 4 + q) * 2 + bg) * 128 + cg) * 256 + (size_t)eb * 8;
        store_f32_agent(&xpart[ib + jj2], vA);
        store_f32_agent(&xpart[ib + 4 + jj2], vB);
      }
      __builtin_amdgcn_s_waitcnt(0);
      if (l == 0) store_u32_agent(&fx[bg * 256 + cg * 2 + w], (unsigned)(t + 1));
      __syncthreads();
      __builtin_amdgcn_sched_barrier(0);
    }
  } else {
    // =============== Layer-2 recurrence ===============
    const int sid = id - 512;
    const int bg = sid & 1, cg = sid >> 1;
    const int b_glob = bg * 32 + eb;
    bfrag breg0[16], breg1[16];
    {
      const int q = lr >> 2, ja = lr & 3;
      const size_t g0 = ((size_t)q * HDIM + cg * 8 + ja) * HDIM + kbase + lkg * 8;
      const size_t g1 = ((size_t)q * HDIM + cg * 8 + 4 + ja) * HDIM + kbase + lkg * 8;
#pragma unroll
      for (int ks = 0; ks < 16; ++ks) {
        breg0[ks] = *reinterpret_cast<const bfrag*>(&whh2[g0 + ks * 32]);
        breg1[ks] = *reinterpret_cast<const bfrag*>(&whh2[g1 + ks * 32]);
      }
    }
    float biasA[4], biasB[4];
#pragma unroll
    for (int q = 0; q < 4; ++q) {
      const int jA = q * HDIM + cg * 8 + jj2;
      biasA[q] = bih2[jA] + bhh2[jA];
      biasB[q] = bih2[jA + 4] + bhh2[jA + 4];
    }
    float cA = 0.f, cB = 0.f;
    unsigned long long* hb = (unsigned long long*)histB;
    const size_t hb0 = (size_t)(kh * 64 + lkg) * 64 + bg * 32 + lr;
    const size_t hb1 = hb0 + 16;
    const unsigned long long* fv = (const unsigned long long*)fL2 + (size_t)bg * 128;
    const unsigned long long* fxp = (const unsigned long long*)fx + (size_t)bg * 128 + cg;

#pragma unroll 1
    for (int t = 0; t < TSTEPS; ++t) {
      {
        const unsigned tt = (unsigned)(t + 1);
        for (;;) {
          unsigned long long v = load_u64_agent(fxp);
          if ((unsigned)v >= tt && (unsigned)(v >> 32) >= tt) break;
          __builtin_amdgcn_s_sleep(1);
        }
      }
      if (t > 0) {
        const unsigned tt = (unsigned)t;
        for (;;) {
          unsigned long long fa = load_u64_agent(&fv[l]);
          unsigned long long fb = load_u64_agent(&fv[64 + l]);
          int ok = ((unsigned)fa >= tt) && ((unsigned)(fa >> 32) >= tt) &&
                   ((unsigned)fb >= tt) && ((unsigned)(fb >> 32) >= tt);
          if (__all(ok)) break;
          __builtin_amdgcn_s_sleep(1);
        }
      }
      __builtin_amdgcn_sched_barrier(0);
      asm volatile("" ::: "memory");

      // xpart loads early (latency hides under the h-GEMM)
      float xpA[4], xpB[4];
#pragma unroll
      for (int q = 0; q < 4; ++q) {
        const size_t ib =
            ((((size_t)(t & 7) * 4 + q) * 2 + bg) * 128 + cg) * 256 + (size_t)eb * 8;
        xpA[q] = load_f32_agent(&xpart[ib + jj2]);
        xpB[q] = load_f32_agent(&xpart[ib + 4 + jj2]);
      }

      const unsigned long long* hin = hb + (size_t)(TSTEPS - t) * HSLOT;
      ffrag a00 = ffrag{0.f,0.f,0.f,0.f}, a01 = ffrag{0.f,0.f,0.f,0.f};
      ffrag a10 = ffrag{0.f,0.f,0.f,0.f}, a11 = ffrag{0.f,0.f,0.f,0.f};
#pragma unroll
      for (int ks = 0; ks < 16; ++ks) {
        union { unsigned long long u[2]; bfrag f; } r0, r1;
        r0.u[0] = hin[hb0 + ks * 256];
        r0.u[1] = hin[8192 + hb0 + ks * 256];
        r1.u[0] = hin[hb1 + ks * 256];
        r1.u[1] = hin[8192 + hb1 + ks * 256];
        a00 = mfma16(r0.f, breg0[ks], a00);
        a01 = mfma16(r0.f, breg1[ks], a01);
        a10 = mfma16(r1.f, breg0[ks], a10);
        a11 = mfma16(r1.f, breg1[ks], a11);
      }
#pragma unroll
      for (int r = 0; r < 4; ++r) {
        gxp[kh][lkg * 4 + r][lr]           = a00[r];
        gxp[kh][lkg * 4 + r][16 + lr]      = a01[r];
        gxp[kh][16 + lkg * 4 + r][lr]      = a10[r];
        gxp[kh][16 + lkg * 4 + r][16 + lr] = a11[r];
      }
      __syncthreads();

      const float giA = gxp[0][eb][jj2]      + gxp[1][eb][jj2]      + xpA[0] + biasA[0];
      const float gfA = gxp[0][eb][4 + jj2]  + gxp[1][eb][4 + jj2]  + xpA[1] + biasA[1];
      const float ggA = gxp[0][eb][8 + jj2]  + gxp[1][eb][8 + jj2]  + xpA[2] + biasA[2];
      const float goA = gxp[0][eb][12 + jj2] + gxp[1][eb][12 + jj2] + xpA[3] + biasA[3];
      const float giB = gxp[0][eb][16 + jj2]      + gxp[1][eb][16 + jj2]      + xpB[0] + biasB[0];
      const float gfB = gxp[0][eb][16 + 4 + jj2]  + gxp[1][eb][16 + 4 + jj2]  + xpB[1] + biasB[1];
      const float ggB = gxp[0][eb][16 + 8 + jj2]  + gxp[1][eb][16 + 8 + jj2]  + xpB[2] + biasB[2];
      const float goB = gxp[0][eb][16 + 12 + jj2] + gxp[1][eb][16 + 12 + jj2] + xpB[3] + biasB[3];
      cA = sigm(gfA) * cA + sigm(giA) * tanhfast(ggA);
      const float hA = sigm(goA) * tanhfast(cA);
      cB = sigm(gfB) * cB + sigm(giB) * tanhfast(ggB);
      const float hB = sigm(goB) * tanhfast(cB);

      unsigned long long* hout = hb + (size_t)(255 - t) * HSLOT;
      store_u16_agent((unsigned short*)(hout + (size_t)cg * 64 + b_glob) + jj2,
                      (unsigned short)f2bs(hA));
      store_u16_agent((unsigned short*)(hout + 8192 + (size_t)cg * 64 + b_glob) + jj2,
                      (unsigned short)f2bs(hB));
      if (t == TSTEPS - 1) {
        const int jA = cg * 8 + jj2;
        out_h2[(size_t)b_glob * HDIM + jA] = hA;
        out_h2[(size_t)b_glob * HDIM + jA + 4] = hB;
        out_c2[(size_t)b_glob * HDIM + jA] = cA;
        out_c2[(size_t)b_glob * HDIM + jA + 4] = cB;
        out_last[(size_t)b_glob * HDIM + jA] = hA;
        out_last[(size_t)b_glob * HDIM + jA + 4] = hB;
      }
      __builtin_amdgcn_s_waitcnt(0);
      if (l == 0) store_u32_agent(&fL2[bg * 256 + cg * 2 + w], (unsigned)(t + 1));
      __syncthreads();
      __builtin_amdgcn_sched_barrier(0);
    }
  }
}

// ---------------- logits = h_T @ W_proj^T + b_proj ----------------
__launch_bounds__(256, 2)
__global__ void logits_kernel(const bf16* __restrict__ hfin,
                              const float* __restrict__ Wp,
                              const float* __restrict__ bp,
                              float* __restrict__ out) {
  const int tid = threadIdx.x;
  const int w = tid >> 6, l = tid & 63;
  const int lr = l & 15, lkg = l >> 4, lk = lkg * 8;
  const int col = blockIdx.x * 64 + w * 16 + lr;
  const float* wrow = &Wp[(size_t)col * HDIM];
  const unsigned long long* hb = (const unsigned long long*)hfin;
  ffrag acc[4];
#pragma unroll
  for (int i = 0; i < 4; ++i) acc[i] = ffrag{0.f, 0.f, 0.f, 0.f};
#pragma unroll 2
  for (int ks = 0; ks < 32; ++ks) {
    const int k = ks * 32 + lk;
    float4 wa = *reinterpret_cast<const float4*>(&wrow[k]);
    float4 wb = *reinterpret_cast<const float4*>(&wrow[k + 4]);
    bfrag bv;
    bv[0] = f2bs(wa.x); bv[1] = f2bs(wa.y); bv[2] = f2bs(wa.z); bv[3] = f2bs(wa.w);
    bv[4] = f2bs(wb.x); bv[5] = f2bs(wb.y); bv[6] = f2bs(wb.z); bv[7] = f2bs(wb.w);
    const size_t kg = (size_t)(ks * 4 + lkg);
#pragma unroll
    for (int i = 0; i < 4; ++i) {
      union { unsigned long long u[2]; bfrag f; } av;
      av.u[0] = hb[kg * 64 + i * 16 + lr];
      av.u[1] = hb[8192 + kg * 64 + i * 16 + lr];
      acc[i] = mfma16(av.f, bv, acc[i]);
    }
  }
  const float bias = bp[col];
#pragma unroll
  for (int i = 0; i < 4; ++i) {
#pragma unroll
    for (int r = 0; r < 4; ++r) {
      const int b = i * 16 + (l >> 4) * 4 + r;
      out[(size_t)b * VOCAB + col] = acc[i][r] + bias;
    }
  }
}

extern "C" void kernel_launch(void* const* d_in, const int* in_sizes, int n_in,
                              void* d_out, int out_size, void* d_ws, size_t ws_size,
                              hipStream_t stream) {
  const int*   ids   = (const int*)d_in[0];
  const float* table = (const float*)d_in[1];
  const float* Wih   = (const float*)d_in[2];
  const float* Whh   = (const float*)d_in[3];
  const float* bih   = (const float*)d_in[4];
  const float* bhh   = (const float*)d_in[5];
  const float* Wp    = (const float*)d_in[6];
  const float* bp    = (const float*)d_in[7];
  float* out = (float*)d_out;

  char* ws = (char*)d_ws;
  const size_t HISTB_SZ = 257ull * 131072ull;                 // 33,685,504
  const size_t OFF_XG  = 0;                                   // 134,217,728
  const size_t OFF_HA  = OFF_XG + (size_t)512 * 16384 * 8 * 2;// histA; slots 0-255 alias xb
  const size_t OFF_HB  = OFF_HA + HISTB_SZ;
  const size_t OFF_WIH = OFF_HB + HISTB_SZ;                   // 16 MB (L1 half reused as xpart)
  const size_t OFF_WHH = OFF_WIH + (size_t)2 * GDIM * HDIM * 2;
  const size_t OFF_SYNC= OFF_WHH + (size_t)2 * GDIM * HDIM * 2;

  bf16* xg    = (bf16*)(ws + OFF_XG);
  bf16* xb    = (bf16*)(ws + OFF_HA);   // embeddings = histA slots 0-255
  bf16* histA = (bf16*)(ws + OFF_HA);
  bf16* histB = (bf16*)(ws + OFF_HB);
  bf16* wihb  = (bf16*)(ws + OFF_WIH);
  bf16* whhb  = (bf16*)(ws + OFF_WHH);
  float* xpart = (float*)(ws + OFF_WIH);  // aliases wihb layer-1 (consumed by gemm<0>)
  unsigned* sync = (unsigned*)(ws + OFF_SYNC);
  unsigned* fL1 = sync;
  unsigned* fL2 = sync + 512;
  unsigned* fx  = sync + 1024;

  (void)hipMemsetAsync(sync, 0, 16384, stream);
  (void)hipMemsetAsync(ws + OFF_HA + 33554432ull, 0, 131072, stream);  // histA slot 256
  (void)hipMemsetAsync(ws + OFF_HB + 33554432ull, 0, 131072, stream);  // histB slot 256

  const int nconv4 = 2 * GDIM * HDIM / 4;
  convert_bf16_kernel<<<nconv4 / 256, 256, 0, stream>>>(Wih, wihb, nconv4);
  convert_bf16_kernel<<<nconv4 / 256, 256, 0, stream>>>(Whh, whhb, nconv4);
  const int nemb4 = BATCH * TSTEPS * HDIM / 4;
  embed_kernel<<<nemb4 / 256, 256, 0, stream>>>(ids, table, xb, nemb4);

  float* out_last   = out;              // (64,1024)
  float* out_logits = out + 65536;      // (64,32000)
  float* out_hn     = out + 2113536;    // (2,64,1024)
  float* out_cn     = out + 2244608;    // (2,64,1024)

  gemm_xg_kernel<<<dim3(GDIM / BNX, (BATCH * TSTEPS) / BMX), 256, 0, stream>>>(
      xb, wihb, bih, bhh, xg);

  fused_lstm_kernel<<<768, 128, 0, stream>>>(
      xg, whhb, whhb + (size_t)GDIM * HDIM, wihb + (size_t)GDIM * HDIM,
      bih + GDIM, bhh + GDIM, histA, histB, xpart,
      out_hn, out_cn, out_hn + BATCH * HDIM, out_cn + BATCH * HDIM, out_last,
      fL1, fL2, fx);

  logits_kernel<<<VOCAB / 64, 256, 0, stream>>>(histB, Wp, bp, out_logits);
}